// Round 4
// baseline (288.490 us; speedup 1.0000x reference)
//
#include <hip/hip_runtime.h>

typedef unsigned int uint32;

#define NN 10000
#define EE_ 80000
#define NODE_ROWS 20000
#define NODE_BLOCKS 79         // ceil(20000/256)
#define EDGE_BLOCKS 625        // 160000/256 exact
#define TREE_BLOCKS 64
#define TOTAL_BLOCKS (TREE_BLOCKS + NODE_BLOCKS + EDGE_BLOCKS)   // 768

#define SLOT 4160              // floats per augmented matrix (65 x 64)
#define FLAG_STRIDE 8          // u32 per flag (32 B spacing)
#define F_NODE_WEFF 124
#define F_EDGE_WEFF 125
#define WEFF_NODE 1024         // f32 offset in ws
#define WEFF_EDGE 1536
#define SLOT_BASE 2048         // f32 offset of slot data

// ---------------------------------------------------------------------------
// device-scope flag sync (cross-XCD safe: agent-scope atomics + threadfence)
// ---------------------------------------------------------------------------
static __device__ __forceinline__ void wait_flag(const uint32* ws_u, int id) {
  if (threadIdx.x == 0) {
    const uint32* p = ws_u + id*FLAG_STRIDE;
    int guard = 0;
    while (__hip_atomic_load(p, __ATOMIC_ACQUIRE, __HIP_MEMORY_SCOPE_AGENT) == 0u) {
      __builtin_amdgcn_s_sleep(2);
      if (++guard > (1 << 20)) break;   // bounded: fail visibly, never hang
    }
  }
  __syncthreads();
}
static __device__ __forceinline__ void set_flag(uint32* ws_u, int id) {
  __syncthreads();                       // all block stores issued (vmcnt drained)
  if (threadIdx.x == 0) {
    __threadfence();                     // agent-scope release (L2 writeback)
    __hip_atomic_store(ws_u + id*FLAG_STRIDE, 1u, __ATOMIC_RELEASE,
                       __HIP_MEMORY_SCOPE_AGENT);
  }
}

// ---------------------------------------------------------------------------
// compose64: D = A ∘ B (augmented 65x64: rows 0..63 = W, row 64 = bias)
// ---------------------------------------------------------------------------
static __device__ void compose64(const float* __restrict__ Wa, const float* __restrict__ ba,
                                 const float* __restrict__ Wb, const float* __restrict__ bb,
                                 float* __restrict__ D,
                                 float* s_at, float* s_b, float* s_bp)
{
  const int t = threadIdx.x;
  // stage A^T: s_at[k*68 + r], col 64 = A bias
  #pragma unroll
  for (int i = 0; i < 17; ++i) {
    int idx = t + i*256;
    if (idx < 4160) {
      int r = idx >> 6, k = idx & 63;
      float v = (r < 64) ? Wa[idx] : ba[k];
      s_at[k*68 + r] = v;
    }
  }
  // stage B linear
  #pragma unroll
  for (int i = 0; i < 4; ++i) {
    int idx4 = t + i*256;
    *(float4*)&s_b[idx4*4] = *(const float4*)&Wb[idx4*4];
  }
  if (t < 16) *(float4*)&s_b[4096 + t*4] = *(const float4*)&bb[t*4];
  __syncthreads();

  const int ti = t >> 4, tj = t & 15;
  float acc[4][4];
  #pragma unroll
  for (int d = 0; d < 4; ++d)
    #pragma unroll
    for (int e = 0; e < 4; ++e) acc[d][e] = 0.f;

  #pragma unroll 4
  for (int k = 0; k < 64; ++k) {
    float4 a4 = *(const float4*)&s_at[k*68 + 4*ti];
    float4 b4 = *(const float4*)&s_b[k*64 + 4*tj];
    float av[4] = {a4.x, a4.y, a4.z, a4.w};
    float bv[4] = {b4.x, b4.y, b4.z, b4.w};
    #pragma unroll
    for (int d = 0; d < 4; ++d)
      #pragma unroll
      for (int e = 0; e < 4; ++e) acc[d][e] += av[d]*bv[e];
  }
  #pragma unroll
  for (int d = 0; d < 4; ++d)
    *(float4*)&D[(4*ti + d)*64 + 4*tj] =
        make_float4(acc[d][0], acc[d][1], acc[d][2], acc[d][3]);

  // bias row: b = bA @ WB + bB  (k-split over 4 waves, LDS reduce)
  {
    int cc = t & 63, kq = t >> 6;
    float p = 0.f;
    #pragma unroll 4
    for (int kk = 0; kk < 16; ++kk) {
      int k = kq*16 + kk;
      p += s_at[k*68 + 64] * s_b[k*64 + cc];
    }
    s_bp[kq*64 + cc] = p;
  }
  __syncthreads();
  if (t < 64)
    D[4096 + t] = s_bp[t] + s_bp[64 + t] + s_bp[128 + t] + s_bp[192 + t] + s_b[4096 + t];
}

// ---------------------------------------------------------------------------
// apply helper
// ---------------------------------------------------------------------------
template<int NF>
static __device__ __forceinline__ void mlp_apply_store(const float* x, const float* sW,
                                                       float* po)
{
  float a[16];
  #pragma unroll
  for (int q = 0; q < 16; ++q) a[q] = sW[NF*16 + q];   // bias row
  #pragma unroll
  for (int j = 0; j < NF; ++j) {
    const float xv = x[j];
    #pragma unroll
    for (int q = 0; q < 16; ++q) a[q] += xv * sW[j*16 + q];
  }
  float4* d = (float4*)po;
  d[0] = make_float4(a[0],  a[1],  a[2],  a[3]);
  d[1] = make_float4(a[4],  a[5],  a[6],  a[7]);
  d[2] = make_float4(a[8],  a[9],  a[10], a[11]);
  d[3] = make_float4(a[12], a[13], a[14], a[15]);
}

// ---------------------------------------------------------------------------
// megakernel: blocks 0..63 = tree (+root-fold); blocks 64..767 = apply
// ---------------------------------------------------------------------------
__global__ __launch_bounds__(256) void mega_kernel(
    const float* __restrict__ nodes, const float* __restrict__ globals_,
    const float* __restrict__ edges, const int* __restrict__ senders,
    const int* __restrict__ receivers,
    const float* __restrict__ nWin, const float* __restrict__ nbin,
    const float* __restrict__ nWhid, const float* __restrict__ nbhid,
    const float* __restrict__ nWout, const float* __restrict__ nbout,
    const float* __restrict__ eWin, const float* __restrict__ ebin,
    const float* __restrict__ eWhid, const float* __restrict__ ebhid,
    const float* __restrict__ eWout, const float* __restrict__ ebout,
    float* __restrict__ ws_f, float* __restrict__ out)
{
  __shared__ float s_at[64*68];   // 4352 f (alias: s_t1 lo / s_aux hi in root-fold)
  __shared__ float s_b[65*64];    // 4160 f
  __shared__ float s_bp[256];
  uint32* ws_u = (uint32*)ws_f;
  const int t = threadIdx.x;

  if (blockIdx.x < TREE_BLOCKS) {
    // ---------------- tree block ----------------
    const int c = blockIdx.x >> 5, m = blockIdx.x & 31;
    const float* Wh = c ? eWhid : nWhid;
    const float* bh = c ? ebhid : nbhid;

    // level 1: compose raw layers 2m, 2m+1
    {
      const int sid = c*62 + m;
      compose64(Wh + (size_t)(2*m)*4096, bh + (2*m)*64,
                Wh + (size_t)(2*m+1)*4096, bh + (2*m+1)*64,
                ws_f + SLOT_BASE + (size_t)sid*SLOT, s_at, s_b, s_bp);
      set_flag(ws_u, sid);
    }
    // levels 2..5
    #pragma unroll
    for (int l = 2; l <= 5; ++l) {
      const int step = 1 << (l-1);
      if (m & (step-1)) return;
      const int j = m >> (l-1);
      const int bprev = (l==2) ? 0 : (l==3) ? 32 : (l==4) ? 48 : 56;
      const int bcur  = (l==2) ? 32 : (l==3) ? 48 : (l==4) ? 56 : 60;
      const int in0 = c*62 + bprev + 2*j;
      const int outp = c*62 + bcur + j;
      wait_flag(ws_u, in0); wait_flag(ws_u, in0 + 1);
      const float* A  = ws_f + SLOT_BASE + (size_t)in0*SLOT;
      const float* Bm = A + SLOT;
      compose64(A, A + 4096, Bm, Bm + 4096,
                ws_f + SLOT_BASE + (size_t)outp*SLOT, s_at, s_b, s_bp);
      set_flag(ws_u, outp);
    }
    if (m != 0) return;

    // ---------------- root-fold (block m==0 per chain) ----------------
    const int din = c ? 7 : 31;
    const float* Win  = c ? eWin  : nWin;
    const float* bin  = c ? ebin  : nbin;
    const float* Wout = c ? eWout : nWout;
    const float* bout = c ? ebout : nbout;
    const float* L = ws_f + SLOT_BASE + (size_t)(c*62 + 60)*SLOT;
    const float* R = L + SLOT;
    float* weff = ws_f + (c ? WEFF_EDGE : WEFF_NODE);
    float* s_t1  = s_at;          // (din+1) x 64, stride 65 (<= 2080 f)
    float* s_aux = s_at + 2176;   // Ain^T (64x34) then T2 (stride 65)

    wait_flag(ws_u, c*62 + 60); wait_flag(ws_u, c*62 + 61);
    // stage L -> s_b ; Ain^T -> s_aux
    #pragma unroll
    for (int i = 0; i < 5; ++i) {
      int i4 = t + i*256;
      if (i4 < 1040) *(float4*)&s_b[i4*4] = *(const float4*)&L[i4*4];
    }
    for (int idx = t; idx < (din+1)*64; idx += 256) {
      int r = idx >> 6, k = idx & 63;
      s_aux[k*34 + r] = (r < din) ? Win[r*64 + k] : bin[k];
    }
    __syncthreads();
    // T1 = Ain ∘ L  -> s_t1
    {
      const int ti = t >> 4, tj = t & 15;
      if (2*ti <= din) {
        float acc[2][4] = {{0.f,0.f,0.f,0.f},{0.f,0.f,0.f,0.f}};
        #pragma unroll 4
        for (int k = 0; k < 64; ++k) {
          float2 a2 = *(const float2*)&s_aux[k*34 + 2*ti];
          float4 h4 = *(const float4*)&s_b[k*64 + 4*tj];
          acc[0][0] += a2.x*h4.x; acc[0][1] += a2.x*h4.y;
          acc[0][2] += a2.x*h4.z; acc[0][3] += a2.x*h4.w;
          acc[1][0] += a2.y*h4.x; acc[1][1] += a2.y*h4.y;
          acc[1][2] += a2.y*h4.z; acc[1][3] += a2.y*h4.w;
        }
        #pragma unroll
        for (int d = 0; d < 2; ++d) {
          int r = 2*ti + d;
          if (r <= din) {
            #pragma unroll
            for (int e = 0; e < 4; ++e) {
              float v = acc[d][e];
              if (r == din) v += s_b[4096 + 4*tj + e];
              s_t1[r*65 + 4*tj + e] = v;
            }
          }
        }
      }
    }
    __syncthreads();
    // stage R -> s_b
    #pragma unroll
    for (int i = 0; i < 5; ++i) {
      int i4 = t + i*256;
      if (i4 < 1040) *(float4*)&s_b[i4*4] = *(const float4*)&R[i4*4];
    }
    __syncthreads();
    // T2 = T1 ∘ R -> s_aux (Ain^T dead)
    {
      const int ti = t >> 4, tj = t & 15;
      if (2*ti <= din) {
        float acc[2][4] = {{0.f,0.f,0.f,0.f},{0.f,0.f,0.f,0.f}};
        #pragma unroll 4
        for (int k = 0; k < 64; ++k) {
          float a0 = s_t1[(2*ti)*65 + k];
          float a1 = (2*ti + 1 <= din) ? s_t1[(2*ti+1)*65 + k] : 0.f;
          float4 h4 = *(const float4*)&s_b[k*64 + 4*tj];
          acc[0][0] += a0*h4.x; acc[0][1] += a0*h4.y;
          acc[0][2] += a0*h4.z; acc[0][3] += a0*h4.w;
          acc[1][0] += a1*h4.x; acc[1][1] += a1*h4.y;
          acc[1][2] += a1*h4.z; acc[1][3] += a1*h4.w;
        }
        #pragma unroll
        for (int d = 0; d < 2; ++d) {
          int r = 2*ti + d;
          if (r <= din) {
            #pragma unroll
            for (int e = 0; e < 4; ++e) {
              float v = acc[d][e];
              if (r == din) v += s_b[4096 + 4*tj + e];
              s_aux[r*65 + 4*tj + e] = v;
            }
          }
        }
      }
    }
    __syncthreads();
    // stage Wout (64x16) + bout -> s_b
    *(float4*)&s_b[t*4] = *(const float4*)&Wout[t*4];
    if (t < 4) *(float4*)&s_b[1024 + t*4] = *(const float4*)&bout[t*4];
    __syncthreads();
    // Weff = T2 ∘ [Wout;bout]
    {
      const int ti = t >> 4, tj = t & 15;
      #pragma unroll
      for (int d = 0; d < 2; ++d) {
        int r = 2*ti + d;
        if (r <= din) {
          float acc = 0.f;
          #pragma unroll 4
          for (int cc = 0; cc < 64; ++cc)
            acc += s_aux[r*65 + cc] * s_b[cc*16 + tj];
          if (r == din) acc += s_b[1024 + tj];
          weff[r*16 + tj] = acc;
        }
      }
    }
    set_flag(ws_u, c ? F_EDGE_WEFF : F_NODE_WEFF);
    return;
  }

  // ---------------- apply block ----------------
  const int ab = blockIdx.x - TREE_BLOCKS;
  const bool is_node = (ab < NODE_BLOCKS);
  wait_flag(ws_u, is_node ? F_NODE_WEFF : F_EDGE_WEFF);
  {
    const float* src = ws_f + (is_node ? WEFF_NODE : WEFF_EDGE);
    const int n = is_node ? 32*16 : 8*16;
    for (int j = t; j < n; j += 256) s_b[j] = src[j];
  }
  __syncthreads();

  if (is_node) {
    const int rn = ab*256 + t;
    if (rn >= NODE_ROWS) return;
    float x[31];
    const float* p = nodes + (size_t)rn*30;
    #pragma unroll
    for (int j = 0; j < 15; ++j) {
      float2 u = *(const float2*)(p + j*2);
      x[2*j]     = u.x;
      x[2*j + 1] = u.y;
    }
    const int b = (rn >= NN) ? 1 : 0;
    x[30] = globals_[b];
    mlp_apply_store<31>(x, s_b, out + (size_t)rn*16);
  } else {
    const int re = (ab - NODE_BLOCKS)*256 + t;   // < 160000 exact
    const int b = (re >= EE_) ? 1 : 0;
    float x[7];
    const float* ep = edges + (size_t)re*3;
    x[0] = ep[0]; x[1] = ep[1]; x[2] = ep[2];
    const int si = senders[re], ri = receivers[re];
    const float* ps = nodes + ((size_t)(b*NN + si))*30;
    const float* pr = nodes + ((size_t)(b*NN + ri))*30;
    const float dx = ps[0] - pr[0];
    const float dy = ps[1] - pr[1];
    const float dz = ps[2] - pr[2];
    x[3] = dx; x[4] = dy; x[5] = dz;
    x[6] = sqrtf(dx*dx + dy*dy + dz*dz);
    mlp_apply_store<7>(x, s_b, out + (size_t)(NODE_ROWS + re)*16);
  }
}

extern "C" void kernel_launch(void* const* d_in, const int* in_sizes, int n_in,
                              void* d_out, int out_size, void* d_ws, size_t ws_size,
                              hipStream_t stream)
{
  const float* nodes    = (const float*)d_in[0];
  const float* globals_ = (const float*)d_in[1];
  const float* edges    = (const float*)d_in[2];
  const int* senders   = (const int*)d_in[3];
  const int* receivers = (const int*)d_in[4];
  const float* nWin  = (const float*)d_in[5];
  const float* nbin  = (const float*)d_in[6];
  const float* nWhid = (const float*)d_in[7];
  const float* nbhid = (const float*)d_in[8];
  const float* nWout = (const float*)d_in[9];
  const float* nbout = (const float*)d_in[10];
  const float* eWin  = (const float*)d_in[11];
  const float* ebin  = (const float*)d_in[12];
  const float* eWhid = (const float*)d_in[13];
  const float* ebhid = (const float*)d_in[14];
  const float* eWout = (const float*)d_in[15];
  const float* ebout = (const float*)d_in[16];
  float* ws  = (float*)d_ws;
  float* out = (float*)d_out;

  // reset dataflow flags (bytes [0, 4096) of ws) every call — deterministic
  hipMemsetAsync(d_ws, 0, 4096, stream);

  mega_kernel<<<TOTAL_BLOCKS, 256, 0, stream>>>(
      nodes, globals_, edges, senders, receivers,
      nWin, nbin, nWhid, nbhid, nWout, nbout,
      eWin, ebin, eWhid, ebhid, eWout, ebout, ws, out);
}

// Round 5
// 65.816 us; speedup vs baseline: 4.3833x; 4.3833x over previous
//
#include <hip/hip_runtime.h>

#define NN 10000
#define EE_ 80000
#define NODE_ROWS 20000
#define NODE_BLOCKS 79         // ceil(20000/256)
#define EDGE_BLOCKS 625        // 160000/256 exact

// ---------------------------------------------------------------------------
// chain_kernel: 32 blocks x 64 threads (1 wave). Block (c,q) evolves column q
// of chain c's 64x16 suffix product right-to-left:
//   v_64 = Wout[:,q];  v_i = Whid[i] @ v_{i+1}  (i = 63..0)
//   beta = sum_i bhid[i]. v_{i+1}   (lane-separable -> 1 FMA/step, reduce once)
// then folds [Win;bin] and bout into column q of W_eff in ws.
// ws layout: [0..512) node W_eff (32x16), [512..640) edge W_eff (8x16).
// ---------------------------------------------------------------------------
__global__ __launch_bounds__(64, 1) void chain_kernel(
    const float* __restrict__ nWin, const float* __restrict__ nbin,
    const float* __restrict__ nWhid, const float* __restrict__ nbhid,
    const float* __restrict__ nWout, const float* __restrict__ nbout,
    const float* __restrict__ eWin, const float* __restrict__ ebin,
    const float* __restrict__ eWhid, const float* __restrict__ ebhid,
    const float* __restrict__ eWout, const float* __restrict__ ebout,
    float* __restrict__ ws)
{
  const int lane = threadIdx.x;          // 0..63 = vector row k
  const int c = blockIdx.x >> 4;         // 0 node, 1 edge
  const int q = blockIdx.x & 15;         // output column
  const float* Win  = c ? eWin  : nWin;
  const float* bin  = c ? ebin  : nbin;
  const float* Whid = c ? eWhid : nWhid;
  const float* bhid = c ? ebhid : nbhid;
  const float* Wout = c ? eWout : nWout;
  const float* bout = c ? ebout : nbout;
  const int din = c ? 7 : 31;
  float* weff = ws + (c ? 512 : 0);

  __shared__ float s_v[64];

  const float* Wrow = Whid + (size_t)lane*64;   // this lane's row base
  float v = Wout[lane*16 + q];                  // v_64[lane]
  float bpart = 0.f;

  // prime wa = row of Whid[63]
  float4 wa[16], wb[16];
  #pragma unroll
  for (int kb = 0; kb < 16; ++kb)
    wa[kb] = *(const float4*)&Wrow[(size_t)63*4096 + kb*4];

  #pragma unroll 1
  for (int ii = 0; ii < 32; ++ii) {
    const int iA = 63 - 2*ii;          // odd step, uses wa, prefetches wb
    // ---- step A (layer iA) ----
    s_v[lane] = v;
    #pragma unroll
    for (int kb = 0; kb < 16; ++kb)    // prefetch W_{iA-1} (iA >= 1 always here)
      wb[kb] = *(const float4*)&Wrow[(size_t)(iA-1)*4096 + kb*4];
    bpart = __builtin_fmaf(bhid[iA*64 + lane], v, bpart);
    __builtin_amdgcn_sched_barrier(0);  // pin ds_write before the broadcast reads
    {
      float a0=0.f, a1=0.f, a2=0.f, a3=0.f;
      #pragma unroll
      for (int kb = 0; kb < 16; ++kb) {
        float4 vv = *(const float4*)&s_v[kb*4];   // same-addr broadcast, no conflict
        a0 = __builtin_fmaf(wa[kb].x, vv.x, a0);
        a1 = __builtin_fmaf(wa[kb].y, vv.y, a1);
        a2 = __builtin_fmaf(wa[kb].z, vv.z, a2);
        a3 = __builtin_fmaf(wa[kb].w, vv.w, a3);
      }
      v = (a0 + a1) + (a2 + a3);
    }
    __builtin_amdgcn_sched_barrier(0);  // all reads done before next overwrite

    const int iB = iA - 1;             // even step, uses wb, prefetches wa
    s_v[lane] = v;
    if (iB > 0) {
      #pragma unroll
      for (int kb = 0; kb < 16; ++kb)
        wa[kb] = *(const float4*)&Wrow[(size_t)(iB-1)*4096 + kb*4];
    }
    bpart = __builtin_fmaf(bhid[iB*64 + lane], v, bpart);
    __builtin_amdgcn_sched_barrier(0);
    {
      float a0=0.f, a1=0.f, a2=0.f, a3=0.f;
      #pragma unroll
      for (int kb = 0; kb < 16; ++kb) {
        float4 vv = *(const float4*)&s_v[kb*4];
        a0 = __builtin_fmaf(wb[kb].x, vv.x, a0);
        a1 = __builtin_fmaf(wb[kb].y, vv.y, a1);
        a2 = __builtin_fmaf(wb[kb].z, vv.z, a2);
        a3 = __builtin_fmaf(wb[kb].w, vv.w, a3);
      }
      v = (a0 + a1) + (a2 + a3);
    }
    __builtin_amdgcn_sched_barrier(0);
  }
  // v == v_0[lane]; bpart holds this lane's share of beta

  // beta_total = sum_k (bpart[k] + bin[k]*v0[k]); then + bout[q]
  float red = __builtin_fmaf(bin[lane], v, bpart);
  #pragma unroll
  for (int off = 32; off > 0; off >>= 1) red += __shfl_xor(red, off, 64);

  // share v0 for the Win fold
  s_v[lane] = v;
  __builtin_amdgcn_sched_barrier(0);

  if (lane == din) {
    weff[din*16 + q] = red + bout[q];
  } else if (lane < din) {
    float a0=0.f, a1=0.f, a2=0.f, a3=0.f;
    const float* wr = Win + (size_t)lane*64;
    #pragma unroll
    for (int kb = 0; kb < 16; ++kb) {
      float4 vv = *(const float4*)&s_v[kb*4];
      float4 wv = *(const float4*)&wr[kb*4];
      a0 = __builtin_fmaf(wv.x, vv.x, a0);
      a1 = __builtin_fmaf(wv.y, vv.y, a1);
      a2 = __builtin_fmaf(wv.z, vv.z, a2);
      a3 = __builtin_fmaf(wv.w, vv.w, a3);
    }
    weff[lane*16 + q] = (a0 + a1) + (a2 + a3);
  }
}

// ---------------------------------------------------------------------------
// apply: blocks [0,79) node rows; rest edge rows. (validated in R3)
// ---------------------------------------------------------------------------
template<int NF>
static __device__ __forceinline__ void mlp_apply_store(const float* x, const float* sW,
                                                       float* po)
{
  float a[16];
  #pragma unroll
  for (int q = 0; q < 16; ++q) a[q] = sW[NF*16 + q];   // bias row
  #pragma unroll
  for (int j = 0; j < NF; ++j) {
    const float xv = x[j];
    #pragma unroll
    for (int q = 0; q < 16; ++q) a[q] += xv * sW[j*16 + q];
  }
  float4* d = (float4*)po;
  d[0] = make_float4(a[0],  a[1],  a[2],  a[3]);
  d[1] = make_float4(a[4],  a[5],  a[6],  a[7]);
  d[2] = make_float4(a[8],  a[9],  a[10], a[11]);
  d[3] = make_float4(a[12], a[13], a[14], a[15]);
}

__global__ __launch_bounds__(256) void apply_kernel(
    const float* __restrict__ nodes, const float* __restrict__ globals_,
    const float* __restrict__ edges, const int* __restrict__ senders,
    const int* __restrict__ receivers, const float* __restrict__ ws,
    float* __restrict__ out)
{
  __shared__ float sW[32*16];
  const bool is_node = (blockIdx.x < NODE_BLOCKS);
  {
    const float* src = is_node ? ws : ws + 512;
    const int n = is_node ? 32*16 : 8*16;
    for (int j = threadIdx.x; j < n; j += 256) sW[j] = src[j];
  }
  __syncthreads();

  if (is_node) {
    const int rn = blockIdx.x*256 + threadIdx.x;
    if (rn >= NODE_ROWS) return;
    float x[31];
    const float* p = nodes + (size_t)rn*30;
    #pragma unroll
    for (int j = 0; j < 15; ++j) {
      float2 u = *(const float2*)(p + j*2);
      x[2*j]     = u.x;
      x[2*j + 1] = u.y;
    }
    const int b = (rn >= NN) ? 1 : 0;
    x[30] = globals_[b];
    mlp_apply_store<31>(x, sW, out + (size_t)rn*16);
  } else {
    const int re = (blockIdx.x - NODE_BLOCKS)*256 + threadIdx.x;  // < 160000 exact
    const int b = (re >= EE_) ? 1 : 0;
    float x[7];
    const float* ep = edges + (size_t)re*3;
    x[0] = ep[0]; x[1] = ep[1]; x[2] = ep[2];
    const int si = senders[re], ri = receivers[re];
    const float* ps = nodes + ((size_t)(b*NN + si))*30;
    const float* pr = nodes + ((size_t)(b*NN + ri))*30;
    const float dx = ps[0] - pr[0];
    const float dy = ps[1] - pr[1];
    const float dz = ps[2] - pr[2];
    x[3] = dx; x[4] = dy; x[5] = dz;
    x[6] = sqrtf(dx*dx + dy*dy + dz*dz);
    mlp_apply_store<7>(x, sW, out + (size_t)(NODE_ROWS + re)*16);
  }
}

extern "C" void kernel_launch(void* const* d_in, const int* in_sizes, int n_in,
                              void* d_out, int out_size, void* d_ws, size_t ws_size,
                              hipStream_t stream)
{
  const float* nodes    = (const float*)d_in[0];
  const float* globals_ = (const float*)d_in[1];
  const float* edges    = (const float*)d_in[2];
  const int* senders   = (const int*)d_in[3];
  const int* receivers = (const int*)d_in[4];
  const float* nWin  = (const float*)d_in[5];
  const float* nbin  = (const float*)d_in[6];
  const float* nWhid = (const float*)d_in[7];
  const float* nbhid = (const float*)d_in[8];
  const float* nWout = (const float*)d_in[9];
  const float* nbout = (const float*)d_in[10];
  const float* eWin  = (const float*)d_in[11];
  const float* ebin  = (const float*)d_in[12];
  const float* eWhid = (const float*)d_in[13];
  const float* ebhid = (const float*)d_in[14];
  const float* eWout = (const float*)d_in[15];
  const float* ebout = (const float*)d_in[16];
  float* ws  = (float*)d_ws;
  float* out = (float*)d_out;

  chain_kernel<<<32, 64, 0, stream>>>(
      nWin, nbin, nWhid, nbhid, nWout, nbout,
      eWin, ebin, eWhid, ebhid, eWout, ebout, ws);

  apply_kernel<<<NODE_BLOCKS + EDGE_BLOCKS, 256, 0, stream>>>(
      nodes, globals_, edges, senders, receivers, ws, out);
}